// Round 11
// baseline (89.986 us; speedup 1.0000x reference)
//
#include <hip/hip_runtime.h>
#include <hip/hip_bf16.h>

#define TT   1024
#define NF   32
#define NB   128
#define HID  16
#define KK   5
#define DD   4
#define FPAD 24
#define XROW (FPAD + TT + FPAD)          // 1072 bf16 per (f,b) row
#define FP2  4
#define H1R  (TT + 2 * FP2)              // 1032 rows of 16 cin bf16
#define WPO  ((size_t)NF * NB * XROW)    // ushort offset of wpack in ws
#define WPSZ ((size_t)NF * 64 * 40)      // wpack ushorts (5 frags x 8 ush)

typedef short short8   __attribute__((ext_vector_type(8)));
typedef short short8_u __attribute__((ext_vector_type(8), aligned(4)));
typedef float floatx4  __attribute__((ext_vector_type(4)));

__device__ inline ushort f2bf(float f) {
    union { float f; uint u; } v; v.f = f;
    uint r = v.u + 0x7fffu + ((v.u >> 16) & 1u);
    return (ushort)(r >> 16);
}
__device__ inline uint cvt_pk_bf16(float lo, float hi) {
    uint r;
    asm("v_cvt_pk_bf16_f32 %0, %1, %2" : "=v"(r) : "v"(lo), "v"(hi));
    return r;
}

// ---- prep: transpose x to (F,B,XROW) bf16 + weight fragment pack ----
__global__ __launch_bounds__(256) void prep_k(
    const float* __restrict__ x, const float* __restrict__ w1,
    const float* __restrict__ w2, ushort* __restrict__ xhi,
    ushort* __restrict__ wpack)
{
    const int tc  = blockIdx.x;
    const int b   = blockIdx.y;
    const int tid = threadIdx.x;

    if (tc == 4) {
        if (b >= NF || tid >= 64) return;
        const int f = b, lane = tid;
        const int g = lane >> 4, crow = lane & 15;
        short8 a0 = {0,0,0,0,0,0,0,0}, a1 = a0, af[3] = {a0, a0, a0};
        if (g == 0) {
            const float* w1f = w1 + (size_t)f * HID * KK + crow * KK;
            #pragma unroll
            for (int j = 0; j < 8; ++j) {
                if (j < 5)           a0[j] = (short)f2bf(w1f[j]);
                if (j >= 1 && j < 6) a1[j] = (short)f2bf(w1f[j - 1]);
            }
        }
        const int cin0 = (g & 1) * 8, dk = g >> 1;
        const float* w2f = w2 + (size_t)f * HID * HID * KK;
        #pragma unroll
        for (int p = 0; p < 3; ++p) {
            int k = 2 * p + dk;
            #pragma unroll
            for (int j = 0; j < 8; ++j)
                af[p][j] = (k < KK) ? (short)f2bf(w2f[crow * (HID * KK) + (cin0 + j) * KK + k]) : (short)0;
        }
        short8* dst = (short8*)wpack + ((size_t)f * 64 + lane) * 5;
        dst[0] = a0; dst[1] = a1; dst[2] = af[0]; dst[3] = af[1]; dst[4] = af[2];
        return;
    }

    __shared__ float ls[256 * 40];

    const float4* xb = (const float4*)(x + ((size_t)b * TT + tc * 256) * NF);
    #pragma unroll
    for (int i = 0; i < 8; ++i) {
        int v = tid + 256 * i;
        float4 val = xb[v];
        int tl = v >> 3, f0 = 4 * (v & 7);
        int col = f0 ^ (4 * (tl >> 5));        // XOR-swizzled column (2-way free)
        *(float4*)&ls[tl * 40 + col] = val;
    }
    __syncthreads();

    const int f  = tid >> 3, tb = tid & 7;
    const int col = f ^ (4 * tb);
    uint hbu[16];
    #pragma unroll
    for (int m = 0; m < 32; m += 2) {
        float v0 = ls[(tb * 32 + m)     * 40 + col];
        float v1 = ls[(tb * 32 + m + 1) * 40 + col];
        hbu[m >> 1] = cvt_pk_bf16(v0, v1);
    }
    size_t di = (size_t)(f * NB + b) * XROW + FPAD + tc * 256 + tb * 32;
    uint4* dh = (uint4*)(xhi + di);
    #pragma unroll
    for (int q = 0; q < 4; ++q)
        dh[q] = make_uint4(hbu[4*q], hbu[4*q+1], hbu[4*q+2], hbu[4*q+3]);

    if (tc == 0) {
        for (int i = tid; i < NF * FPAD; i += 256) {
            int fz = i / FPAD, e = i % FPAD;
            xhi[(size_t)(fz * NB + b) * XROW + e] = 0;
        }
    } else if (tc == 3) {
        for (int i = tid; i < NF * FPAD; i += 256) {
            int fz = i / FPAD, e = i % FPAD;
            xhi[(size_t)(fz * NB + b) * XROW + FPAD + TT + e] = 0;
        }
    }
}

// ---- conv1: xhi -> h1g[(f*NB+b)][t+FP2][cin] bf16 (coalesced C-frag stores) ----
__global__ __launch_bounds__(256) void conv1_k(
    const ushort* __restrict__ xhi, const ushort* __restrict__ wpack,
    const float* __restrict__ b1, ushort* __restrict__ h1g)
{
    const int f = blockIdx.x & 31;
    const int b = blockIdx.x >> 5;
    const int tid  = threadIdx.x;
    const int wave = tid >> 6;
    const int lane = tid & 63;
    const int g    = lane >> 4;
    const int crow = lane & 15;
    const bool odd = (crow & 1) != 0;

    const short8* wl = (const short8*)wpack + ((size_t)f * 64 + lane) * 5;
    const short8 a0 = wl[0], a1 = wl[1];
    const float4 b1v = *(const float4*)(b1 + f * HID + 4 * g);

    const ushort* xh = xhi + (size_t)(f * NB + b) * XROW;
    ushort* hb = h1g + (size_t)(f * NB + b) * (H1R * 16);

    // zero pad rows (t = -4..-1 and 1024..1027), done by wave 0 only
    if (wave == 0 && lane < 32) {
        if (lane < 16) ((uint2*)hb)[lane] = make_uint2(0u, 0u);                  // rows 0..3
        else ((uint2*)(hb + (TT + FP2) * 16))[lane - 16] = make_uint2(0u, 0u);   // rows 1028..1031
    }

    const int t0 = wave * 256;
    const ushort* xbase = xh + (t0 + (crow & ~1) + (FPAD - 2));

    #pragma unroll
    for (int batch = 0; batch < 2; ++batch) {
        short8 bh[8];
        #pragma unroll
        for (int i = 0; i < 8; ++i)
            bh[i] = *(const short8_u*)(xbase + 16 * (8 * batch + i));
        #pragma unroll
        for (int i = 0; i < 8; ++i) {
            const int us = 8 * batch + i;
            floatx4 ae = {b1v.x, b1v.y, b1v.z, b1v.w};
            floatx4 ao = ae;
            ae = __builtin_amdgcn_mfma_f32_16x16x32_bf16(a0, bh[i], ae, 0, 0, 0);
            ao = __builtin_amdgcn_mfma_f32_16x16x32_bf16(a1, bh[i], ao, 0, 0, 0);
            float h0  = fmaxf(odd ? ao[0] : ae[0], 0.f);
            float h1v = fmaxf(odd ? ao[1] : ae[1], 0.f);
            float h2  = fmaxf(odd ? ao[2] : ae[2], 0.f);
            float h3  = fmaxf(odd ? ao[3] : ae[3], 0.f);
            const int row = t0 + 16 * us + crow + FP2;
            *(uint2*)(hb + row * 16 + 4 * g) = make_uint2(cvt_pk_bf16(h0, h1v), cvt_pk_bf16(h2, h3));
        }
    }
}

// ---- conv2: h1g -> relu -> pool -> GEMV -> out. No LDS tile, pure stream. ----
__global__ __launch_bounds__(256) void conv2_k(
    const ushort* __restrict__ h1g, const ushort* __restrict__ wpack,
    const float* __restrict__ b2, const float* __restrict__ pw,
    const float* __restrict__ pb, float* __restrict__ out)
{
    const int f = blockIdx.x & 31;
    const int b = blockIdx.x >> 5;
    const int tid  = threadIdx.x;
    const int wave = tid >> 6;
    const int lane = tid & 63;
    const int g    = lane >> 4;
    const int crow = lane & 15;
    const int dk   = g >> 1;

    __shared__ float pool_lds[HID * DD];

    const short8* wl = (const short8*)wpack + ((size_t)f * 64 + lane) * 5;
    const short8 af0 = wl[2], af1 = wl[3], af2 = wl[4];
    const float4 b2v = *(const float4*)(b2 + f * HID + 4 * g);

    const ushort* hb = h1g + (size_t)(f * NB + b) * (H1R * 16);
    const int t0 = wave * 256;
    // B-frag for (st,p): h1[cin0..+8][t_out + 2p + dk - 2], t_out = t0+16st+crow
    // row = t + FP2 -> ushort offset = (t0+16st+crow+2p+dk+2)*16 + 8*(g&1)
    const ushort* hl = hb + ((size_t)(t0 + crow + dk + 2) * 16 + 8 * (g & 1));

    float psum[4] = {0.f, 0.f, 0.f, 0.f};
    #pragma unroll
    for (int st = 0; st < 16; ++st) {
        floatx4 acc = {b2v.x, b2v.y, b2v.z, b2v.w};
        acc = __builtin_amdgcn_mfma_f32_16x16x32_bf16(af0, *(const short8_u*)(hl + 256 * st +  0), acc, 0, 0, 0);
        acc = __builtin_amdgcn_mfma_f32_16x16x32_bf16(af1, *(const short8_u*)(hl + 256 * st + 32), acc, 0, 0, 0);
        acc = __builtin_amdgcn_mfma_f32_16x16x32_bf16(af2, *(const short8_u*)(hl + 256 * st + 64), acc, 0, 0, 0);
        #pragma unroll
        for (int rr = 0; rr < 4; ++rr) psum[rr] += fmaxf(acc[rr], 0.f);
    }

    // ---- pool reduce across the 16 col-lanes of each group ----
    #pragma unroll
    for (int rr = 0; rr < 4; ++rr) {
        float v = psum[rr];
        v += __shfl_xor(v, 1, 64);
        v += __shfl_xor(v, 2, 64);
        v += __shfl_xor(v, 4, 64);
        v += __shfl_xor(v, 8, 64);
        if (crow == 0) pool_lds[(4 * g + rr) * DD + wave] = v * (1.f / 256.f);
    }
    __syncthreads();

    // ---- final GEMV ----
    if (tid < DD) {
        const float* pwr = pw + ((size_t)f * DD + tid) * (HID * DD);
        float o = pb[f * DD + tid];
        #pragma unroll
        for (int i = 0; i < HID * DD; ++i) o = fmaf(pwr[i], pool_lds[i], o);
        out[((size_t)b * NF + f) * DD + tid] = o;
    }
}

extern "C" void kernel_launch(void* const* d_in, const int* in_sizes, int n_in,
                              void* d_out, int out_size, void* d_ws, size_t ws_size,
                              hipStream_t stream) {
    const float* x  = (const float*)d_in[0];
    // d_in[1] = lengths (unused by reference)
    const float* w1 = (const float*)d_in[2];
    const float* b1 = (const float*)d_in[3];
    const float* w2 = (const float*)d_in[4];
    const float* b2 = (const float*)d_in[5];
    const float* pw = (const float*)d_in[6];
    const float* pb = (const float*)d_in[7];
    float* out = (float*)d_out;

    ushort* xhi   = (ushort*)d_ws;
    ushort* wpack = xhi + WPO;
    ushort* h1g   = wpack + WPSZ;     // byte offset 16B-aligned

    prep_k <<<dim3(5, NB),  dim3(256), 0, stream>>>(x, w1, w2, xhi, wpack);
    conv1_k<<<dim3(NF * NB), dim3(256), 0, stream>>>(xhi, wpack, b1, h1g);
    conv2_k<<<dim3(NF * NB), dim3(256), 0, stream>>>(h1g, wpack, b2, pw, pb, out);
}

// Round 12
// 71.684 us; speedup vs baseline: 1.2553x; 1.2553x over previous
//
#include <hip/hip_runtime.h>
#include <hip/hip_bf16.h>

#define TT   1024
#define NF   32
#define NB   128
#define HID  16
#define KK   5
#define DD   4
#define FPAD 24
#define XROW (FPAD + TT + FPAD)          // 1072 bf16 per (f,b) row
#define WPO  ((size_t)NF * NB * XROW)    // ushort offset of weight pack in ws

typedef short short8   __attribute__((ext_vector_type(8)));
typedef short short8_u __attribute__((ext_vector_type(8), aligned(4)));
typedef float floatx4  __attribute__((ext_vector_type(4)));

__device__ inline ushort f2bf(float f) {
    union { float f; uint u; } v; v.f = f;
    uint r = v.u + 0x7fffu + ((v.u >> 16) & 1u);
    return (ushort)(r >> 16);
}
__device__ inline uint cvt_pk_bf16(float lo, float hi) {
    uint r;
    asm("v_cvt_pk_bf16_f32 %0, %1, %2" : "=v"(r) : "v"(lo), "v"(hi));
    return r;
}

// ---- pre-kernel: transpose x to (F,B,XROW) bf16 + weight fragment pack ----
__global__ __launch_bounds__(256) void prep_k(
    const float* __restrict__ x, const float* __restrict__ w1,
    const float* __restrict__ w2, ushort* __restrict__ xhi,
    ushort* __restrict__ wpack)
{
    const int tc  = blockIdx.x;
    const int b   = blockIdx.y;
    const int tid = threadIdx.x;

    if (tc == 4) {
        if (b >= NF || tid >= 64) return;
        const int f = b, lane = tid;
        const int g = lane >> 4, crow = lane & 15;
        short8 a0 = {0,0,0,0,0,0,0,0}, a1 = a0, af[3] = {a0, a0, a0};
        if (g == 0) {
            const float* w1f = w1 + (size_t)f * HID * KK + crow * KK;
            #pragma unroll
            for (int j = 0; j < 8; ++j) {
                if (j < 5)           a0[j] = (short)f2bf(w1f[j]);
                if (j >= 1 && j < 6) a1[j] = (short)f2bf(w1f[j - 1]);
            }
        }
        const int cin0 = (g & 1) * 8, dk = g >> 1;
        const float* w2f = w2 + (size_t)f * HID * HID * KK;
        #pragma unroll
        for (int p = 0; p < 3; ++p) {
            int k = 2 * p + dk;
            #pragma unroll
            for (int j = 0; j < 8; ++j)
                af[p][j] = (k < KK) ? (short)f2bf(w2f[crow * (HID * KK) + (cin0 + j) * KK + k]) : (short)0;
        }
        short8* dst = (short8*)wpack + ((size_t)f * 64 + lane) * 5;
        dst[0] = a0; dst[1] = a1; dst[2] = af[0]; dst[3] = af[1]; dst[4] = af[2];
        return;
    }

    __shared__ float ls[256 * 40];

    const float4* xb = (const float4*)(x + ((size_t)b * TT + tc * 256) * NF);
    #pragma unroll
    for (int i = 0; i < 8; ++i) {
        int v = tid + 256 * i;
        float4 val = xb[v];
        int tl = v >> 3, f0 = 4 * (v & 7);
        int col = f0 ^ (4 * (tl >> 5));        // XOR-swizzled column (2-way free)
        *(float4*)&ls[tl * 40 + col] = val;
    }
    __syncthreads();

    const int f  = tid >> 3, tb = tid & 7;
    const int col = f ^ (4 * tb);
    uint hbu[16];
    #pragma unroll
    for (int m = 0; m < 32; m += 2) {
        float v0 = ls[(tb * 32 + m)     * 40 + col];
        float v1 = ls[(tb * 32 + m + 1) * 40 + col];
        hbu[m >> 1] = cvt_pk_bf16(v0, v1);
    }
    size_t di = (size_t)(f * NB + b) * XROW + FPAD + tc * 256 + tb * 32;
    uint4* dh = (uint4*)(xhi + di);
    #pragma unroll
    for (int q = 0; q < 4; ++q)
        dh[q] = make_uint4(hbu[4*q], hbu[4*q+1], hbu[4*q+2], hbu[4*q+3]);

    if (tc == 0) {
        for (int i = tid; i < NF * FPAD; i += 256) {
            int fz = i / FPAD, e = i % FPAD;
            xhi[(size_t)(fz * NB + b) * XROW + e] = 0;
        }
    } else if (tc == 3) {
        for (int i = tid; i < NF * FPAD; i += 256) {
            int fz = i / FPAD, e = i % FPAD;
            xhi[(size_t)(fz * NB + b) * XROW + FPAD + TT + e] = 0;
        }
    }
}

// ---- fused kernel: 1024 threads = 16 waves = whole (b,f) ----
// Tile geometry identical to R6 (288 rows x 16 cin, swizzled, per 256-col
// segment), but each tile is built by 4 waves (sub = wave&3, 4-5 subtiles
// each) and consumed by the same 4 waves (ti = sub). One barrier between.
// 36.9 KB / 16 waves -> VGPR-bound occupancy (target <=64 regs, 32 waves/CU).
__global__ __launch_bounds__(1024) void fused_kernel(
    const ushort* __restrict__ xhi, const ushort* __restrict__ wpack,
    const float* __restrict__ b1, const float* __restrict__ b2,
    const float* __restrict__ pw, const float* __restrict__ pb,
    float* __restrict__ out)
{
    const int f = blockIdx.x & 31;
    const int b = blockIdx.x >> 5;
    const int tid  = threadIdx.x;
    const int wave = tid >> 6;
    const int seg  = wave >> 2;
    const int sub  = wave & 3;
    const int lane = tid & 63;
    const int g    = lane >> 4;
    const int crow = lane & 15;
    const bool odd = (crow & 1) != 0;

    __shared__ __align__(64) ushort tiles[4][4608];   // 4 x 9.2 KB
    float* pool_lds = (float*)&tiles[0][0];            // overlay after barrier
    ushort* tile = tiles[seg];

    const short8* wl = (const short8*)wpack + ((size_t)f * 64 + lane) * 5;
    const short8 a0 = wl[0], a1 = wl[1];
    const float4 b1v = *(const float4*)(b1 + f * HID + 4 * g);

    // conv1 write base (R6 algebra; us = sub + 4u -> +256*sub + 1024*u)
    const int woffbase = (crow >> 1) * 32
                       + (((((crow & 1) << 1) | (g >> 1)) ^ ((crow >> 1) & 3)) << 3)
                       + ((g & 1) << 2);
    ushort* wdst = tile + woffbase + 256 * sub;

    const int t0seg = seg * 256;
    const ushort* xh = xhi + (size_t)(f * NB + b) * XROW;
    const ushort* xbase = xh + (t0seg - 16 + 16 * sub + (crow & ~1) + (FPAD - 2));

    const int nsub = (sub < 2) ? 5 : 4;    // wave-uniform: 18 subtiles over 4 waves

    short8 bh[5];
    #pragma unroll
    for (int u = 0; u < 5; ++u)
        if (u < nsub) bh[u] = *(const short8_u*)(xbase + 64 * u);

    #pragma unroll
    for (int u = 0; u < 5; ++u) {
        if (u < nsub) {
            const int tbase = t0seg - 16 + 16 * (sub + 4 * u);
            uint2 wv;
            if (tbase < 0 || tbase >= TT) {      // wave-uniform: exact halo zeros
                wv = make_uint2(0u, 0u);
            } else {
                floatx4 ae = {b1v.x, b1v.y, b1v.z, b1v.w};
                floatx4 ao = ae;
                ae = __builtin_amdgcn_mfma_f32_16x16x32_bf16(a0, bh[u], ae, 0, 0, 0);
                ao = __builtin_amdgcn_mfma_f32_16x16x32_bf16(a1, bh[u], ao, 0, 0, 0);
                float h0  = fmaxf(odd ? ao[0] : ae[0], 0.f);
                float h1v = fmaxf(odd ? ao[1] : ae[1], 0.f);
                float h2  = fmaxf(odd ? ao[2] : ae[2], 0.f);
                float h3  = fmaxf(odd ? ao[3] : ae[3], 0.f);
                wv = make_uint2(cvt_pk_bf16(h0, h1v), cvt_pk_bf16(h2, h3));
            }
            *(uint2*)(wdst + 1024 * u) = wv;
        }
    }

    // conv2 weights loaded after conv1 (shorter live ranges; hides under barrier)
    const short8 af0 = wl[2], af1 = wl[3], af2 = wl[4];
    const float4 b2v = *(const float4*)(b2 + f * HID + 4 * g);
    const int dk = g >> 1;
    const int E  = crow + dk + 14;               // read row r = E + 2p + sub*64 + st*16
    const int Ch = ((E & 1) << 1) | (g & 1);
    const int tioff = 1024 * sub;
    const ushort* tp0 = tile + ((E >> 1) + 0) * 32 + ((Ch ^ (((E >> 1) + 0) & 3)) << 3) + tioff;
    const ushort* tp1 = tile + ((E >> 1) + 1) * 32 + ((Ch ^ (((E >> 1) + 1) & 3)) << 3) + tioff;
    const ushort* tp2 = tile + ((E >> 1) + 2) * 32 + ((Ch ^ (((E >> 1) + 2) & 3)) << 3) + tioff;

    __syncthreads();   // tiles complete

    float psum[4] = {0.f, 0.f, 0.f, 0.f};
    #pragma unroll
    for (int st = 0; st < 4; ++st) {
        const int off = st * 256;
        floatx4 acc = {b2v.x, b2v.y, b2v.z, b2v.w};
        acc = __builtin_amdgcn_mfma_f32_16x16x32_bf16(af0, *(const short8*)(tp0 + off), acc, 0, 0, 0);
        acc = __builtin_amdgcn_mfma_f32_16x16x32_bf16(af1, *(const short8*)(tp1 + off), acc, 0, 0, 0);
        acc = __builtin_amdgcn_mfma_f32_16x16x32_bf16(af2, *(const short8*)(tp2 + off), acc, 0, 0, 0);
        #pragma unroll
        for (int rr = 0; rr < 4; ++rr) psum[rr] += fmaxf(acc[rr], 0.f);
    }

    __syncthreads();   // all tile reads done; safe to overlay pool on tiles[0]

    // per-wave partial (64 cols); pool_lds[cout][wave], wave = 4*seg + sub
    #pragma unroll
    for (int rr = 0; rr < 4; ++rr) {
        float v = psum[rr];
        v += __shfl_xor(v, 1, 64);
        v += __shfl_xor(v, 2, 64);
        v += __shfl_xor(v, 4, 64);
        v += __shfl_xor(v, 8, 64);
        if (crow == 0) pool_lds[(4 * g + rr) * 16 + wave] = v;
    }
    __syncthreads();

    // ---- final GEMV: out[b, f*4 + d] ----
    if (tid < DD) {
        const float* pwr = pw + ((size_t)f * DD + tid) * (HID * DD);
        float o = pb[f * DD + tid];
        #pragma unroll
        for (int c = 0; c < HID; ++c) {
            #pragma unroll
            for (int s = 0; s < DD; ++s) {
                float pv = pool_lds[c * 16 + 4 * s + 0] + pool_lds[c * 16 + 4 * s + 1]
                         + pool_lds[c * 16 + 4 * s + 2] + pool_lds[c * 16 + 4 * s + 3];
                o = fmaf(pwr[c * DD + s], pv * (1.f / 256.f), o);
            }
        }
        out[((size_t)b * NF + f) * DD + tid] = o;
    }
}

extern "C" void kernel_launch(void* const* d_in, const int* in_sizes, int n_in,
                              void* d_out, int out_size, void* d_ws, size_t ws_size,
                              hipStream_t stream) {
    const float* x  = (const float*)d_in[0];
    // d_in[1] = lengths (unused by reference)
    const float* w1 = (const float*)d_in[2];
    const float* b1 = (const float*)d_in[3];
    const float* w2 = (const float*)d_in[4];
    const float* b2 = (const float*)d_in[5];
    const float* pw = (const float*)d_in[6];
    const float* pb = (const float*)d_in[7];
    float* out = (float*)d_out;

    ushort* xhi   = (ushort*)d_ws;
    ushort* wpack = xhi + WPO;

    prep_k<<<dim3(5, NB), dim3(256), 0, stream>>>(x, w1, w2, xhi, wpack);
    fused_kernel<<<dim3(NF * NB), dim3(1024), 0, stream>>>(xhi, wpack, b1, b2, pw, pb, out);
}

// Round 13
// 40.925 us; speedup vs baseline: 2.1988x; 1.7516x over previous
//
#include <hip/hip_runtime.h>
#include <hip/hip_bf16.h>

#define TT   1024
#define NF   32
#define NB   128
#define HID  16
#define KK   5
#define DD   4
#define FPAD 24
#define XROW (FPAD + TT + FPAD)          // 1072 bf16 per (f,b) row
#define WPO  ((size_t)NF * NB * XROW)    // ushort offset of weight pack in ws

typedef short short8   __attribute__((ext_vector_type(8)));
typedef short short8_u __attribute__((ext_vector_type(8), aligned(4)));
typedef float floatx4  __attribute__((ext_vector_type(4)));

__device__ inline ushort f2bf(float f) {
    union { float f; uint u; } v; v.f = f;
    uint r = v.u + 0x7fffu + ((v.u >> 16) & 1u);
    return (ushort)(r >> 16);
}
__device__ inline uint cvt_pk_bf16(float lo, float hi) {
    uint r;
    asm("v_cvt_pk_bf16_f32 %0, %1, %2" : "=v"(r) : "v"(lo), "v"(hi));
    return r;
}

// ---- pre-kernel: transpose x to (F,B,XROW) bf16 + weight fragment pack ----
__global__ __launch_bounds__(256) void prep_k(
    const float* __restrict__ x, const float* __restrict__ w1,
    const float* __restrict__ w2, ushort* __restrict__ xhi,
    ushort* __restrict__ wpack)
{
    const int tc  = blockIdx.x;
    const int b   = blockIdx.y;
    const int tid = threadIdx.x;

    if (tc == 4) {
        if (b >= NF || tid >= 64) return;
        const int f = b, lane = tid;
        const int g = lane >> 4, crow = lane & 15;
        short8 a0 = {0,0,0,0,0,0,0,0}, a1 = a0, af[3] = {a0, a0, a0};
        if (g == 0) {
            const float* w1f = w1 + (size_t)f * HID * KK + crow * KK;
            #pragma unroll
            for (int j = 0; j < 8; ++j) {
                if (j < 5)           a0[j] = (short)f2bf(w1f[j]);
                if (j >= 1 && j < 6) a1[j] = (short)f2bf(w1f[j - 1]);
            }
        }
        const int cin0 = (g & 1) * 8, dk = g >> 1;
        const float* w2f = w2 + (size_t)f * HID * HID * KK;
        #pragma unroll
        for (int p = 0; p < 3; ++p) {
            int k = 2 * p + dk;
            #pragma unroll
            for (int j = 0; j < 8; ++j)
                af[p][j] = (k < KK) ? (short)f2bf(w2f[crow * (HID * KK) + (cin0 + j) * KK + k]) : (short)0;
        }
        short8* dst = (short8*)wpack + ((size_t)f * 64 + lane) * 5;
        dst[0] = a0; dst[1] = a1; dst[2] = af[0]; dst[3] = af[1]; dst[4] = af[2];
        return;
    }

    __shared__ float ls[256 * 40];

    const float4* xb = (const float4*)(x + ((size_t)b * TT + tc * 256) * NF);
    #pragma unroll
    for (int i = 0; i < 8; ++i) {
        int v = tid + 256 * i;
        float4 val = xb[v];
        int tl = v >> 3, f0 = 4 * (v & 7);
        int col = f0 ^ (4 * (tl >> 5));        // XOR-swizzled column (2-way free)
        *(float4*)&ls[tl * 40 + col] = val;
    }
    __syncthreads();

    const int f  = tid >> 3, tb = tid & 7;
    const int col = f ^ (4 * tb);
    uint hbu[16];
    #pragma unroll
    for (int m = 0; m < 32; m += 2) {
        float v0 = ls[(tb * 32 + m)     * 40 + col];
        float v1 = ls[(tb * 32 + m + 1) * 40 + col];
        hbu[m >> 1] = cvt_pk_bf16(v0, v1);
    }
    size_t di = (size_t)(f * NB + b) * XROW + FPAD + tc * 256 + tb * 32;
    uint4* dh = (uint4*)(xhi + di);
    #pragma unroll
    for (int q = 0; q < 4; ++q)
        dh[q] = make_uint4(hbu[4*q], hbu[4*q+1], hbu[4*q+2], hbu[4*q+3]);

    if (tc == 0) {
        for (int i = tid; i < NF * FPAD; i += 256) {
            int fz = i / FPAD, e = i % FPAD;
            xhi[(size_t)(fz * NB + b) * XROW + e] = 0;
        }
    } else if (tc == 3) {
        for (int i = tid; i < NF * FPAD; i += 256) {
            int fz = i / FPAD, e = i % FPAD;
            xhi[(size_t)(fz * NB + b) * XROW + FPAD + TT + e] = 0;
        }
    }
}

// ---- fused branch kernel (R6 structure + improved bank swizzle) ----
// Tile: 288 rows x 16 cin bf16 per wave (144 lines of 64B = 2 rows).
// chunk = Ch ^ swz(L), swz(L) = (L ^ (L>>2)) & 3  -> lines L, L+4 now land
// in different bank groups (R6's L&3 swizzle left them colliding).
// swz(L+8) = swz(L)^2 -> dual even/odd base pointers, selected at compile
// time in the unrolled loops (offsets stay pure immediates).
__global__ __launch_bounds__(256, 4) void fused_kernel(
    const ushort* __restrict__ xhi, const ushort* __restrict__ wpack,
    const float* __restrict__ b1, const float* __restrict__ b2,
    const float* __restrict__ pw, const float* __restrict__ pb,
    float* __restrict__ out)
{
    const int f = blockIdx.x & 31;
    const int b = blockIdx.x >> 5;
    const int tid  = threadIdx.x;
    const int wave = tid >> 6;
    const int lane = tid & 63;
    const int g    = lane >> 4;
    const int crow = lane & 15;
    const bool odd = (crow & 1) != 0;

    __shared__ __align__(64) ushort tiles[4][4608];   // 144 lines * 32 ushorts per wave
    __shared__ float  pool_lds[HID * DD];
    ushort* tile = tiles[wave];

    // ---- packed weights: 5 coalesced 16B loads ----
    const short8* wl = (const short8*)wpack + ((size_t)f * 64 + lane) * 5;
    const short8 a0 = wl[0], a1 = wl[1];
    const short8 af0 = wl[2], af1 = wl[3], af2 = wl[4];
    const float4 b1v = *(const float4*)(b1 + f * HID + 4 * g);
    const float4 b2v = *(const float4*)(b2 + f * HID + 4 * g);
    const int dk = g >> 1;

    // ---- lane-constant swizzled LDS bases (new swz, e/o parity pairs) ----
    const int L0  = crow >> 1;
    const int Chw = ((crow & 1) << 1) | (g >> 1);
    const int woffbase = L0 * 32 + ((Chw ^ ((L0 ^ (L0 >> 2)) & 3)) << 3) + ((g & 1) << 2);
    ushort* wdste = tile + woffbase;             // even us (swz unchanged)
    ushort* wdsto = tile + (woffbase ^ 16);      // odd  us (chunk ^= 2)

    const int E  = crow + dk + 14;               // read row r = E + 2p + ti*64 + st*16
    const int Ch = ((E & 1) << 1) | (g & 1);
    const int Lp0 = (E >> 1) + 0, Lp1 = (E >> 1) + 1, Lp2 = (E >> 1) + 2;
    const int o0 = Lp0 * 32 + ((Ch ^ ((Lp0 ^ (Lp0 >> 2)) & 3)) << 3);
    const int o1 = Lp1 * 32 + ((Ch ^ ((Lp1 ^ (Lp1 >> 2)) & 3)) << 3);
    const int o2 = Lp2 * 32 + ((Ch ^ ((Lp2 ^ (Lp2 >> 2)) & 3)) << 3);
    const ushort *tp0e = tile + o0, *tp0o = tile + (o0 ^ 16);
    const ushort *tp1e = tile + o1, *tp1o = tile + (o1 ^ 16);
    const ushort *tp2e = tile + o2, *tp2o = tile + (o2 ^ 16);

    const int t0seg = wave * 256;
    const ushort* xh = xhi + (size_t)(f * NB + b) * XROW;

    // ---- prefetch all 18 conv1 B-fragments (1 base + imm offsets) ----
    const ushort* xbase = xh + (t0seg - 16 + (crow & ~1) + (FPAD - 2));
    short8 bh[18];
    #pragma unroll
    for (int us = 0; us < 18; ++us)
        bh[us] = *(const short8_u*)(xbase + 16 * us);

    // ---- conv1: 18 subtiles -> swizzled LDS tile rows [0,288) ----
    #pragma unroll
    for (int us = 0; us < 18; ++us) {
        const int tbase = t0seg - 16 + 16 * us;
        uint2 wv;
        if (tbase < 0 || tbase >= TT) {        // wave-uniform: zero halo rows
            wv = make_uint2(0u, 0u);
        } else {
            floatx4 ae = {b1v.x, b1v.y, b1v.z, b1v.w};
            floatx4 ao = ae;
            ae = __builtin_amdgcn_mfma_f32_16x16x32_bf16(a0, bh[us], ae, 0, 0, 0);
            ao = __builtin_amdgcn_mfma_f32_16x16x32_bf16(a1, bh[us], ao, 0, 0, 0);
            float h0  = fmaxf(odd ? ao[0] : ae[0], 0.f);
            float h1v = fmaxf(odd ? ao[1] : ae[1], 0.f);
            float h2  = fmaxf(odd ? ao[2] : ae[2], 0.f);
            float h3  = fmaxf(odd ? ao[3] : ae[3], 0.f);
            wv = make_uint2(cvt_pk_bf16(h0, h1v), cvt_pk_bf16(h2, h3));
        }
        *(uint2*)(((us & 1) ? wdsto : wdste) + 256 * us) = wv;
    }

    // ---- conv2 + relu + pool (imm-offset reads, e/o base by st parity) ----
    float psum[4] = {0.f, 0.f, 0.f, 0.f};
    #pragma unroll
    for (int ti = 0; ti < 4; ++ti) {
        #pragma unroll
        for (int st = 0; st < 4; ++st) {
            const int off = ti * 1024 + st * 256;
            const ushort* p0 = (st & 1) ? tp0o : tp0e;
            const ushort* p1 = (st & 1) ? tp1o : tp1e;
            const ushort* p2 = (st & 1) ? tp2o : tp2e;
            floatx4 acc = {b2v.x, b2v.y, b2v.z, b2v.w};
            acc = __builtin_amdgcn_mfma_f32_16x16x32_bf16(af0, *(const short8*)(p0 + off), acc, 0, 0, 0);
            acc = __builtin_amdgcn_mfma_f32_16x16x32_bf16(af1, *(const short8*)(p1 + off), acc, 0, 0, 0);
            acc = __builtin_amdgcn_mfma_f32_16x16x32_bf16(af2, *(const short8*)(p2 + off), acc, 0, 0, 0);
            #pragma unroll
            for (int rr = 0; rr < 4; ++rr) psum[rr] += fmaxf(acc[rr], 0.f);
        }
    }

    // ---- pool reduce across the 16 col-lanes of each group ----
    #pragma unroll
    for (int rr = 0; rr < 4; ++rr) {
        float v = psum[rr];
        v += __shfl_xor(v, 1, 64);
        v += __shfl_xor(v, 2, 64);
        v += __shfl_xor(v, 4, 64);
        v += __shfl_xor(v, 8, 64);
        if (crow == 0) pool_lds[(4 * g + rr) * DD + wave] = v * (1.f / 256.f);
    }
    __syncthreads();

    // ---- final GEMV ----
    if (tid < DD) {
        const float* pwr = pw + ((size_t)f * DD + tid) * (HID * DD);
        float o = pb[f * DD + tid];
        #pragma unroll
        for (int i = 0; i < HID * DD; ++i) o = fmaf(pwr[i], pool_lds[i], o);
        out[((size_t)b * NF + f) * DD + tid] = o;
    }
}

extern "C" void kernel_launch(void* const* d_in, const int* in_sizes, int n_in,
                              void* d_out, int out_size, void* d_ws, size_t ws_size,
                              hipStream_t stream) {
    const float* x  = (const float*)d_in[0];
    // d_in[1] = lengths (unused by reference)
    const float* w1 = (const float*)d_in[2];
    const float* b1 = (const float*)d_in[3];
    const float* w2 = (const float*)d_in[4];
    const float* b2 = (const float*)d_in[5];
    const float* pw = (const float*)d_in[6];
    const float* pb = (const float*)d_in[7];
    float* out = (float*)d_out;

    ushort* xhi   = (ushort*)d_ws;
    ushort* wpack = xhi + WPO;

    prep_k<<<dim3(5, NB), dim3(256), 0, stream>>>(x, w1, w2, xhi, wpack);
    fused_kernel<<<dim3(NF * NB), dim3(256), 0, stream>>>(xhi, wpack, b1, b2, pw, pb, out);
}